// Round 5
// baseline (386.320 us; speedup 1.0000x reference)
//
#include <hip/hip_runtime.h>

#define HWN 2304
#define HT  4
#define JT  64
#define NTHR 512

using bf16x8 = __attribute__((ext_vector_type(8))) short;
using f32x4  = __attribute__((ext_vector_type(4))) float;

// LDS: bf16 tiles, 40-short (80B) rows -> ds_read_b128 16B-aligned, low-conflict.
// Epilogue reuses as fp32 out-stage [2048][4].
union Lds {
    struct {
        unsigned short sA[128 * 40];   // [hw*32 + b][40]
        unsigned short bA[128 * 40];   // [hw*32 + b][40]
        unsigned short wB[256 * 40];   // [hw*64 + j][40]
    } st;
    float outst[2048 * 4];             // [b*64+j][hw]
};

__device__ __forceinline__ unsigned short f2bf(float x) {  // RNE fp32->bf16
    unsigned u = __float_as_uint(x);
    u += 0x7FFF + ((u >> 16) & 1);
    return (unsigned short)(u >> 16);
}

__global__ __launch_bounds__(NTHR, 4)
void lc_main(const float* __restrict__ xg, const float* __restrict__ bg,
             const float* __restrict__ wg, float* __restrict__ outg,
             float* __restrict__ rep, int repmask) {
    __shared__ Lds L;

    // XCD-chunked swizzle: 1152 blocks, 8 XCDs, 144 contiguous units each.
    const int bid  = blockIdx.x;
    const int unit = (bid & 7) * 144 + (bid >> 3);
    const int hc  = unit >> 1;          // hw chunk, adjacent on same XCD
    const int jh  = unit & 1;
    const int hw0 = hc * HT;
    const int j0  = jh * JT;

    const int t   = threadIdx.x;
    const int wv  = t >> 6;             // 8 waves
    const int l   = t & 63;
    const int mw  = wv & 1;             // b-half (0..15 / 16..31)
    const int nq  = wv >> 1;            // j-tile of 16 (0..3)
    const int l15 = l & 15;
    const int blk = l >> 4;             // k-group 0..3

    // staging maps
    const int kp = t & 15;              // k-pair (x/b)
    const int bb = t >> 4;              // b-row 0..31 (x/b)
    const int jj = t & 63;              // j (w)
    const int ii = t >> 6;              // i-quad 0..7 (w)

    const float* xbase = xg + hw0;
    const float* bbase = bg + hw0;
    const float* wbase = wg + (size_t)(j0 + jj) * HWN + hw0;

    f32x4 rx[2], rb[2], rw[4];

    auto load_chunk = [&](int kc) {
#pragma unroll
        for (int d = 0; d < 2; ++d) {
            const int row = bb * 128 + kc * 32 + kp * 2 + d;
            rx[d] = *(const f32x4*)(xbase + (size_t)row * HWN);
            rb[d] = *(const f32x4*)(bbase + (size_t)row * HWN);
        }
#pragma unroll
        for (int e = 0; e < 4; ++e) {
            const int i = kc * 32 + ii * 4 + e;
            rw[e] = *(const f32x4*)(wbase + (size_t)i * (128 * HWN));
        }
    };

    auto stage = [&]() {
#pragma unroll
        for (int h = 0; h < 4; ++h) {
            ushort2 s2 = { f2bf(rx[0][h] + rb[0][h]), f2bf(rx[1][h] + rb[1][h]) };
            ushort2 b2 = { f2bf(rb[0][h]), f2bf(rb[1][h]) };
            const int off = (h * 32 + bb) * 40 + kp * 2;
            *(ushort2*)&L.st.sA[off] = s2;
            *(ushort2*)&L.st.bA[off] = b2;
        }
#pragma unroll
        for (int h = 0; h < 4; ++h) {
            ushort4 w4 = { f2bf(rw[0][h]), f2bf(rw[1][h]),
                           f2bf(rw[2][h]), f2bf(rw[3][h]) };
            *(ushort4*)&L.st.wB[(h * 64 + jj) * 40 + ii * 4] = w4;
        }
    };

    f32x4 accS[4];
    f32x4 accB = {0.f, 0.f, 0.f, 0.f};
#pragma unroll
    for (int h = 0; h < 4; ++h) accS[h] = {0.f, 0.f, 0.f, 0.f};

    load_chunk(0);
    for (int kc = 0; kc < 4; ++kc) {
        __syncthreads();                 // A: all compute(kc-1) LDS reads done
        stage();                         // vmcnt waits for chunk-kc loads here
        __syncthreads();                 // B: staging visible
        if (kc < 3) load_chunk(kc + 1);  // in flight across compute(kc)
#pragma unroll
        for (int h = 0; h < 4; ++h) {
            bf16x8 aS = *(const bf16x8*)&L.st.sA[(h * 32 + mw * 16 + l15) * 40 + blk * 8];
            bf16x8 aB = *(const bf16x8*)&L.st.bA[(h * 32 + mw * 16 + l15) * 40 + blk * 8];
            bf16x8 wf = *(const bf16x8*)&L.st.wB[(h * 64 + nq * 16 + l15) * 40 + blk * 8];
            accS[h] = __builtin_amdgcn_mfma_f32_16x16x32_bf16(aS, wf, accS[h], 0, 0, 0);
            accB    = __builtin_amdgcn_mfma_f32_16x16x32_bf16(aB, wf, accB,    0, 0, 0);
        }
    }

    __syncthreads();   // frag reads done; reuse LDS as out-stage
    // C/D layout (verified): col = lane&15, row = 4*(lane>>4) + reg
#pragma unroll
    for (int r = 0; r < 4; ++r) {
        const int p = (mw * 16 + blk * 4 + r) * 64 + nq * 16 + l15;
#pragma unroll
        for (int h = 0; h < 4; ++h)
            L.outst[p * 4 + h] = accS[h][r];
    }
    __syncthreads();
#pragma unroll
    for (int i = 0; i < 4; ++i) {
        const int p = i * 512 + t;
        const float4 v = *(const float4*)&L.outst[p * 4];
        const int br = p >> 6, jl = p & 63;
        *(float4*)(outg + (size_t)(br * 128 + j0 + jl) * HWN + hw0) = v;
    }
    // b-path partials: replicated accumulators kill same-line atomic convoy
    const int rr = bid & repmask;
#pragma unroll
    for (int r = 0; r < 4; ++r)
        atomicAdd(&rep[rr * 4096 + (mw * 16 + blk * 4 + r) * 128 + j0 + nq * 16 + l15],
                  accB[r]);
}

__global__ __launch_bounds__(576)
void lc_fix(float* __restrict__ outg, const float* __restrict__ rep, int nrep) {
    const int bj = blockIdx.x;                 // (b*128+j) row
    __shared__ float sm;
    if (threadIdx.x < 64) {
        float v = (threadIdx.x < nrep) ? rep[threadIdx.x * 4096 + bj] : 0.f;
        v += __shfl_xor(v, 32); v += __shfl_xor(v, 16); v += __shfl_xor(v, 8);
        v += __shfl_xor(v, 4);  v += __shfl_xor(v, 2);  v += __shfl_xor(v, 1);
        if (threadIdx.x == 0) sm = v * (1.0f / 2304.0f);
    }
    __syncthreads();
    const float m = sm;
    float4* p = (float4*)(outg + (size_t)bj * HWN) + threadIdx.x;
    float4 v = *p;
    v.x -= m; v.y -= m; v.z -= m; v.w -= m;
    *p = v;
}

extern "C" void kernel_launch(void* const* d_in, const int* in_sizes, int n_in,
                              void* d_out, int out_size, void* d_ws, size_t ws_size,
                              hipStream_t stream) {
    const float* x = (const float*)d_in[0];
    const float* b = (const float*)d_in[1];
    const float* w = (const float*)d_in[2];
    float* out = (float*)d_out;
    float* rep = (float*)d_ws;

    int nrep = 1;
    while (nrep < 64 && (size_t)(nrep * 2) * 4096 * sizeof(float) <= ws_size) nrep <<= 1;

    hipMemsetAsync(rep, 0, (size_t)nrep * 4096 * sizeof(float), stream);
    lc_main<<<1152, NTHR, 0, stream>>>(x, b, w, out, rep, nrep - 1);
    lc_fix<<<4096, 576, 0, stream>>>(out, rep, nrep);
}